// Round 5
// baseline (45.488 us; speedup 1.0000x reference)
//
#include <hip/hip_runtime.h>
#include <math.h>

#define PD 68                  // 64 + 2*2 halo
#define PD2 (PD * PD)          // 4624
#define PVOL (PD * PD * PD)    // 314432
#define ZT 4                   // centers per thread (z-column)

// arg(exp2) = KE2*u*h(u) + CW2*d2 ;  u = 1 - dot
// KE2 = -2/radians(20)^2 * log2(e) ; CW2 = -0.5625 * log2(e)
#define KE2 (-23.68045839f)
#define CW2 (-0.8115159605f)

// ---------------- pass 1: normalize + zero-pad + zero accumulators -----------

__global__ __launch_bounds__(256) void pad_normalize_kernel(
    const float* __restrict__ n_pred,   // (2,3,64,64,64)
    const float* __restrict__ src,      // (2,1,64,64,64)
    float4* __restrict__ q,             // (2,68,68,68) padded
    double* __restrict__ acc,           // [0]=total [1]=count
    unsigned long long* __restrict__ cnt)
{
    int idx = blockIdx.x * 256 + threadIdx.x;
    if (idx == 0) { acc[0] = 0.0; acc[1] = 0.0; *cnt = 0ull; }
    if (idx >= 2 * PVOL) return;
    int b = idx / PVOL;
    int r = idx - b * PVOL;
    int z = r / PD2;
    int r2 = r - z * PD2;
    int y = r2 / PD;
    int x = r2 - y * PD;
    int gx = x - 2, gy = y - 2, gz = z - 2;
    float4 v = make_float4(0.f, 0.f, 0.f, 0.f);
    if ((unsigned)gx < 64u && (unsigned)gy < 64u && (unsigned)gz < 64u) {
        const size_t cs = 262144;  // 64^3
        size_t vox = ((size_t)gz * 64 + gy) * 64 + gx;
        size_t off = (size_t)b * 3 * cs + vox;
        float xx = n_pred[off];
        float yy = n_pred[off + cs];
        float zz = n_pred[off + 2 * cs];
        float inv = 1.0f / fmaxf(sqrtf(xx * xx + yy * yy + zz * zz), 1e-6f);
        float m = (src[(size_t)b * cs + vox] > 0.0f) ? 1.0f : 0.0f;  // sig>0.5
        v = make_float4(xx * inv, yy * inv, zz * inv, m);
    }
    q[idx] = v;
}

// ---------------- pass 2: half-stencil, z-column register reuse --------------
// Each thread owns ZT=4 centers along z. A neighbor value loaded at tap-z
// serves up to 3 centers (as its dz=0 / dz=1 / dz=2 tap), cutting loads from
// 62 to 37.5 per voxel. Positive-half stencil (62 of 124 taps): w symmetric =>
// total and count are exactly half the full sums; the ratio is unchanged.

__global__ __launch_bounds__(256) void stencil_col_kernel(
    const float4* __restrict__ q, double* __restrict__ acc,
    unsigned long long* __restrict__ cnt, float* __restrict__ out, int nblocks)
{
    int x = threadIdx.x & 63;
    int y = blockIdx.x * 4 + (threadIdx.x >> 6);
    int z0 = blockIdx.y * ZT;
    int b = blockIdx.z;
    const float4* base =
        q + (size_t)b * PVOL + ((size_t)(z0 + 2) * PD + (y + 2)) * PD + (x + 2);

    float4 cc[ZT];
#pragma unroll
    for (int k = 0; k < ZT; ++k) cc[k] = base[(size_t)k * PD2];

    float tot = 0.0f, cf = 0.0f;

    auto app = [&](const float4& c, const float4& nb, float coff2) {
        float dot = fmaf(c.x, nb.x, fmaf(c.y, nb.y, c.z * nb.z));
        float u = 1.0f - dot;
        // theta^2 = 2*u*P(u)^2, asin series, deg 4 (rel bias < 3e-6)
        float p = fmaf(u, 1.8990885e-3f, 5.5803571e-3f);
        p = fmaf(u, p, 1.8750000e-2f);
        p = fmaf(u, p, 8.3333333e-2f);
        p = fmaf(u, p, 1.0f);
        float uh = u * p * p;
        float w = exp2f(fmaf(KE2, uh, coff2));  // w_dist * w_theta
        float g = nb.w * c.w;                   // both masks (0/1)
        tot = fmaf(w, g, tot);
        cf += g;
    };

#pragma unroll
    for (int k = 0; k < ZT + 2; ++k) {      // tap z = z0 + k
#pragma unroll
        for (int dy = -2; dy <= 2; ++dy) {
#pragma unroll
            for (int dx = -2; dx <= 2; ++dx) {
                float4 nb = base[(size_t)k * PD2 + dy * PD + dx];
                // dz = 0 role (half-plane subset), center k
                if (k < ZT && (dy > 0 || (dy == 0 && dx > 0)))
                    app(cc[k], nb, CW2 * (float)(dy * dy + dx * dx));
                // dz = 1 role, center k-1
                if (k >= 1 && k - 1 < ZT)
                    app(cc[k - 1], nb, CW2 * (float)(1 + dy * dy + dx * dx));
                // dz = 2 role, center k-2
                if (k >= 2 && k - 2 < ZT)
                    app(cc[k - 2], nb, CW2 * (float)(4 + dy * dy + dx * dx));
            }
        }
    }

    // 64-lane wave reduction.
#pragma unroll
    for (int s = 32; s > 0; s >>= 1) {
        tot += __shfl_down(tot, s, 64);
        cf  += __shfl_down(cf, s, 64);
    }
    __shared__ float sd[4], sc[4];
    int wid = threadIdx.x >> 6, lane = threadIdx.x & 63;
    if (lane == 0) { sd[wid] = tot; sc[wid] = cf; }
    __syncthreads();
    if (threadIdx.x == 0) {
        atomicAdd(&acc[0], (double)(sd[0] + sd[1] + sd[2] + sd[3]));
        atomicAdd(&acc[1], (double)(sc[0] + sc[1] + sc[2] + sc[3]));
        __threadfence();
        unsigned long long done = atomicAdd(cnt, 1ull) + 1ull;
        if (done == (unsigned long long)nblocks) {
            double T = atomicAdd(&acc[0], 0.0);
            double C = atomicAdd(&acc[1], 0.0);
            out[0] = (C == 0.0) ? 0.0f : (float)(T / C);
        }
    }
}

// ---------------- fallback (fused, single kernel) if ws too small ------------

#define TILE 8
#define HALO 2
#define LDIM 12
#define LSZ  1728
#define NVOX 512

__global__ __launch_bounds__(256) void repulsion_fused_kernel(
    const float* __restrict__ n_pred, const float* __restrict__ src,
    double* __restrict__ acc)
{
    __shared__ float4 sn[LSZ];
    __shared__ float rd[4], rc[4];
    const int tx = blockIdx.x * TILE, ty = blockIdx.y * TILE;
    const int b = blockIdx.z >> 3, tz = (blockIdx.z & 7) * TILE;
    const size_t cs = 262144;
    const float* npb = n_pred + (size_t)b * 3 * cs;
    const float* spb = src + (size_t)b * cs;
    for (int i = threadIdx.x; i < LSZ; i += 256) {
        int lx = i % LDIM, t = i / LDIM, ly = t % LDIM, lz = t / LDIM;
        int gx = tx + lx - HALO, gy = ty + ly - HALO, gz = tz + lz - HALO;
        float4 v = make_float4(0.f, 0.f, 0.f, 0.f);
        if ((unsigned)gx < 64u && (unsigned)gy < 64u && (unsigned)gz < 64u) {
            size_t off = ((size_t)gz * 64 + gy) * 64 + gx;
            float xx = npb[off], yy = npb[cs + off], zz = npb[2 * cs + off];
            float inv = 1.0f / fmaxf(sqrtf(xx * xx + yy * yy + zz * zz), 1e-6f);
            float m = (spb[off] > 0.0f) ? 1.0f : 0.0f;
            v = make_float4(xx * inv, yy * inv, zz * inv, m);
        }
        sn[i] = v;
    }
    __syncthreads();
    float tot = 0.0f, cf = 0.0f;
    for (int v = threadIdx.x; v < NVOX; v += 256) {
        int lx = (v & 7) + HALO, ly = ((v >> 3) & 7) + HALO, lz = (v >> 6) + HALO;
        int ci = (lz * LDIM + ly) * LDIM + lx;
        float4 c = sn[ci];
        if (c.w == 0.0f) continue;
#pragma unroll
        for (int dz = -2; dz <= 2; ++dz)
#pragma unroll
            for (int dy = -2; dy <= 2; ++dy)
#pragma unroll
                for (int dx = -2; dx <= 2; ++dx) {
                    if (dz == 0 && dy == 0 && dx == 0) continue;
                    const float coff2 =
                        CW2 * (float)(dz * dz + dy * dy + dx * dx);
                    float4 nb = sn[ci + (dz * LDIM + dy) * LDIM + dx];
                    float dot = fmaf(c.x, nb.x, fmaf(c.y, nb.y, c.z * nb.z));
                    float u = 1.0f - dot;
                    float p = fmaf(u, 1.8990885e-3f, 5.5803571e-3f);
                    p = fmaf(u, p, 1.8750000e-2f);
                    p = fmaf(u, p, 8.3333333e-2f);
                    p = fmaf(u, p, 1.0f);
                    float uh = u * p * p;
                    float w = exp2f(fmaf(KE2, uh, coff2));
                    tot = fmaf(w, nb.w, tot);
                    cf += nb.w;
                }
    }
#pragma unroll
    for (int s = 32; s > 0; s >>= 1) {
        tot += __shfl_down(tot, s, 64);
        cf  += __shfl_down(cf, s, 64);
    }
    int wid = threadIdx.x >> 6, lane = threadIdx.x & 63;
    if (lane == 0) { rd[wid] = tot; rc[wid] = cf; }
    __syncthreads();
    if (threadIdx.x == 0) {
        atomicAdd(&acc[0], (double)rd[0] + rd[1] + rd[2] + rd[3]);
        atomicAdd(&acc[1], (double)rc[0] + rc[1] + rc[2] + rc[3]);
    }
}

__global__ void zero_acc_kernel(double* acc) { acc[0] = 0.0; acc[1] = 0.0; }

__global__ void finalize_kernel(const double* acc, float* out) {
    out[0] = (acc[1] == 0.0) ? 0.0f : (float)(acc[0] / acc[1]);
}

// ---------------- launch -----------------------------------------------------

extern "C" void kernel_launch(void* const* d_in, const int* in_sizes, int n_in,
                              void* d_out, int out_size, void* d_ws, size_t ws_size,
                              hipStream_t stream) {
    const float* n_pred = (const float*)d_in[0];
    const float* src    = (const float*)d_in[1];

    const size_t vol_bytes = (size_t)2 * PVOL * sizeof(float4);  // 10,061,824
    const size_t need = vol_bytes + 2 * sizeof(double) + sizeof(unsigned long long);

    if (ws_size >= need) {
        float4* q = (float4*)d_ws;
        double* acc = (double*)((char*)d_ws + vol_bytes);
        unsigned long long* cnt = (unsigned long long*)(acc + 2);
        int nblk = (2 * PVOL + 255) / 256;  // 2457
        pad_normalize_kernel<<<nblk, 256, 0, stream>>>(n_pred, src, q, acc, cnt);
        dim3 grid(16, 64 / ZT, 2);          // (y-tiles, z-tiles, batch) = 512 blocks
        stencil_col_kernel<<<grid, 256, 0, stream>>>(q, acc, cnt, (float*)d_out,
                                                     (int)(grid.x * grid.y * grid.z));
    } else {
        double* acc = (double*)d_ws;
        zero_acc_kernel<<<1, 1, 0, stream>>>(acc);
        dim3 grid(8, 8, 16);
        repulsion_fused_kernel<<<grid, 256, 0, stream>>>(n_pred, src, acc);
        finalize_kernel<<<1, 1, 0, stream>>>(acc, (float*)d_out);
    }
}